// Round 2
// baseline (361.190 us; speedup 1.0000x reference)
//
#include <hip/hip_runtime.h>

#define TL 2048
#define NHEAD 8
#define NLOC 4

typedef __attribute__((ext_vector_type(4))) float f32x4;
typedef __attribute__((ext_vector_type(8))) __bf16 bf16x8;
typedef __attribute__((ext_vector_type(8))) unsigned short u16x8;

static __device__ __forceinline__ unsigned short f2bf(float f) {
    unsigned u = __float_as_uint(f);
    u = (u + 0x7FFFu + ((u >> 16) & 1u)) >> 16;
    return (unsigned short)u;
}
static __device__ __forceinline__ float bf2f(unsigned short u) {
    return __uint_as_float(((unsigned)u) << 16);
}
static __device__ __forceinline__ void gl_lds16(const void* g, void* l) {
    __builtin_amdgcn_global_load_lds(
        (const __attribute__((address_space(1))) void*)g,
        (__attribute__((address_space(3))) void*)l, 16, 0, 0);
}

// rel_scores[h', r] = dot(rel_pos_w[r, h'*64:+64], mlp_w[h'])  -> bf16 [4][4096]
__global__ __launch_bounds__(256) void relscore_kernel(
    const float* __restrict__ rel_pos_w, const float* __restrict__ mlp_w,
    unsigned short* __restrict__ rel_sb) {
    int r = blockIdx.x;      // 0..4094
    int t = threadIdx.x;
    int w = t >> 6, lane = t & 63;
    float v = rel_pos_w[r * 256 + t] * mlp_w[t];
#pragma unroll
    for (int off = 32; off; off >>= 1) v += __shfl_xor(v, off);
    if (lane == 0) rel_sb[w * 4096 + r] = f2bf(v);
}

// v_term[(b*4+h')*L + k] = dot(value[b,4+h',k,:], mlp_w[h'])  -> bf16
__global__ __launch_bounds__(256) void vterm_kernel(
    const float* __restrict__ value, const float* __restrict__ mlp_w,
    unsigned short* __restrict__ vtb) {
    int t = threadIdx.x;
    int lane = t & 63;
    int w = blockIdx.x * 4 + (t >> 6);
    int k = w & (TL - 1);
    int hp = (w >> 11) & 3;
    int b = w >> 13;
    float v = value[((size_t)((b * NHEAD + NLOC + hp) * TL + k) << 6) + lane] *
              mlp_w[hp * 64 + lane];
#pragma unroll
    for (int off = 32; off; off >>= 1) v += __shfl_xor(v, off);
    if (lane == 0) vtb[w] = f2bf(v);
}

// Per (bh, kt): K tile -> bf16 swizzled [64 k][8 chunks], V tile -> bf16
// transposed+swizzled [64 d][8 chunks].  Chunk c of row r stored at c^(r&7).
__global__ __launch_bounds__(256) void preconv_kernel(
    const float* __restrict__ key, const float* __restrict__ value,
    unsigned short* __restrict__ Kb, unsigned short* __restrict__ Vtb) {
    __shared__ float Vf[64][66];
    int blk = blockIdx.x;            // bh*32 + kt
    int t = threadIdx.x;
    size_t src = (size_t)blk * 4096; // tile origin in f32 elements (64 rows x 64)
    size_t dst = (size_t)blk * 4096; // tile origin in u16 elements

    // K: direct convert, swizzled store
#pragma unroll
    for (int i = 0; i < 2; ++i) {
        int ch = t + i * 256;
        int row = ch >> 3, c = ch & 7;
        const float* kp = key + src + row * 64 + c * 8;
        f32x4 a = *(const f32x4*)kp;
        f32x4 bb = *(const f32x4*)(kp + 4);
        u16x8 o;
#pragma unroll
        for (int j = 0; j < 4; ++j) { o[j] = f2bf(a[j]); o[4 + j] = f2bf(bb[j]); }
        *(u16x8*)&Kb[dst + row * 64 + ((c ^ (row & 7)) << 3)] = o;
    }
    // V: coalesced load to LDS, transpose, swizzled store
    {
        int row = t >> 2, q4 = t & 3;
        const float* vp = value + src + row * 64 + q4 * 16;
#pragma unroll
        for (int j = 0; j < 4; ++j)
            *(f32x4*)&Vf[row][q4 * 16 + j * 4] = *(const f32x4*)(vp + j * 4);
    }
    __syncthreads();
#pragma unroll
    for (int i = 0; i < 2; ++i) {
        int ch = t + i * 256;
        int dr = ch >> 3, c = ch & 7;
        u16x8 o;
#pragma unroll
        for (int j = 0; j < 8; ++j) o[j] = f2bf(Vf[c * 8 + j][dr]);
        *(u16x8*)&Vtb[dst + dr * 64 + ((c ^ (dr & 7)) << 3)] = o;
    }
}

// Flash attention: 1 block = 1 (b,h) x 64 q-rows; 4 waves x 16 q each.
// Double-buffered global_load_lds staging of preconverted swizzled bf16 tiles.
__global__ __launch_bounds__(256, 3) void attn_kernel(
    const float* __restrict__ query,
    const unsigned short* __restrict__ Kb, const unsigned short* __restrict__ Vtb,
    const unsigned short* __restrict__ rel_sb, const unsigned short* __restrict__ vtb,
    float* __restrict__ out) {

    __shared__ __align__(16) unsigned char smem[50432];
    unsigned short* Ks0  = (unsigned short*)smem;             // [2][4096] u16
    unsigned short* Vt0  = (unsigned short*)(smem + 16384);   // [2][4096] u16
    unsigned short* relb = (unsigned short*)(smem + 32768);   // [4096] bf16
    unsigned short* bias0 = (unsigned short*)(smem + 40960);  // [2][64] bf16
    unsigned short* Pb   = (unsigned short*)(smem + 41216);   // [4][16*72] u16

    int bid = blockIdx.x;
    int bh = bid >> 5;                 // (b,h) major for K/V L2 locality
    int qb = 31 - (bid & 31);          // heavy q-blocks first
    int h = bh & 7;
    int b = bh >> 3;
    int q0 = qb << 6;
    int t = threadIdx.x;
    int wave = t >> 6, lane = t & 63;
    int l15 = lane & 15, l4 = lane >> 4;
    bool islocal = (h >= NLOC);

    size_t base = (size_t)bh * TL * 64;
    const unsigned short* Ktiles = Kb + (size_t)bh * 32 * 4096;
    const unsigned short* Vtiles = Vtb + (size_t)bh * 32 * 4096;
    const unsigned short* vtp =
        vtb + (islocal ? (size_t)((b * NLOC + h - NLOC) * TL) : 0);

    // ---- prologue: async-stage tile 0; copy relb + bias[0] ----
    gl_lds16(Ktiles + t * 8, Ks0 + t * 8);
    gl_lds16(Ktiles + 2048 + t * 8, Ks0 + 2048 + t * 8);
    gl_lds16(Vtiles + t * 8, Vt0 + t * 8);
    gl_lds16(Vtiles + 2048 + t * 8, Vt0 + 2048 + t * 8);
    if (islocal) {
        const u16x8* src = (const u16x8*)(rel_sb + (h - NLOC) * 4096);
        u16x8* dst = (u16x8*)relb;
        dst[t] = src[t];
        dst[t + 256] = src[t + 256];
        if (t < 8) *(u16x8*)&bias0[t * 8] = *(const u16x8*)&vtp[t * 8];
    }

    int qt = q0 + wave * 16;
    int q = qt + l15;

    // Q fragments, pre-scaled by 1/sqrt(dk) = 0.125 (exact in bf16)
    bf16x8 qf0, qf1;
    {
        const float* qsrc = query + base + (size_t)q * 64 + l4 * 8;
        f32x4 a = *(const f32x4*)qsrc;
        f32x4 bb = *(const f32x4*)(qsrc + 4);
        f32x4 c = *(const f32x4*)(qsrc + 32);
        f32x4 d = *(const f32x4*)(qsrc + 36);
        u16x8 u0, u1;
#pragma unroll
        for (int j = 0; j < 4; ++j) {
            u0[j] = f2bf(a[j] * 0.125f); u0[4 + j] = f2bf(bb[j] * 0.125f);
            u1[j] = f2bf(c[j] * 0.125f); u1[4 + j] = f2bf(d[j] * 0.125f);
        }
        qf0 = __builtin_bit_cast(bf16x8, u0);
        qf1 = __builtin_bit_cast(bf16x8, u1);
    }

    float m = -1e30f, lsum = 0.0f;
    f32x4 acc0 = {0.f, 0.f, 0.f, 0.f};
    f32x4 acc1 = acc0, acc2 = acc0, acc3 = acc0;
    unsigned short* Pw = Pb + wave * (16 * 72);

    __syncthreads();   // tile 0 + relb + bias ready (drains vmcnt & lgkm)

    int cur = 0;
    for (int kt = 0; kt <= qb; ++kt) {
        unsigned short* Ks = Ks0 + cur * 4096;
        unsigned short* Vt = Vt0 + cur * 4096;
        unsigned short* bias = bias0 + cur * 64;

        // ---- prefetch tile kt+1 into the other buffer (async) ----
        if (kt < qb) {
            int nb = cur ^ 1;
            unsigned short* Ksn = Ks0 + nb * 4096;
            unsigned short* Vtn = Vt0 + nb * 4096;
            const unsigned short* gk = Ktiles + (size_t)(kt + 1) * 4096;
            const unsigned short* gv = Vtiles + (size_t)(kt + 1) * 4096;
            gl_lds16(gk + t * 8, Ksn + t * 8);
            gl_lds16(gk + 2048 + t * 8, Ksn + 2048 + t * 8);
            gl_lds16(gv + t * 8, Vtn + t * 8);
            gl_lds16(gv + 2048 + t * 8, Vtn + 2048 + t * 8);
            if (islocal && t < 8)
                *(u16x8*)&bias0[nb * 64 + t * 8] =
                    *(const u16x8*)&vtp[(kt + 1) * 64 + t * 8];
        }

        int k0 = kt << 6;
        bool diag = (kt == qb);
        int s16max = diag ? wave : 3;   // skip fully-masked S sub-tiles

        // ---- S^T = mfma(K, Q): row = k, col = q ----
        f32x4 sfr[4];
        for (int s16 = 0; s16 <= s16max; ++s16) {
            int r = s16 * 16 + l15;
            int sw = r & 7;
            const bf16x8 kf0 = *(const bf16x8*)&Ks[r * 64 + ((l4 ^ sw) << 3)];
            const bf16x8 kf1 = *(const bf16x8*)&Ks[r * 64 + (((4 + l4) ^ sw) << 3)];
            f32x4 z = {0.f, 0.f, 0.f, 0.f};
            z = __builtin_amdgcn_mfma_f32_16x16x32_bf16(kf0, qf0, z, 0, 0, 0);
            z = __builtin_amdgcn_mfma_f32_16x16x32_bf16(kf1, qf1, z, 0, 0, 0);
            sfr[s16] = z;
        }

        // ---- online softmax (per-lane q-row state) ----
        float sv[16];
        float tmax = -1e30f;
        for (int s16 = 0; s16 <= s16max; ++s16) {
#pragma unroll
            for (int rg = 0; rg < 4; ++rg) {
                int kk = s16 * 16 + l4 * 4 + rg;
                int k = k0 + kk;
                float s = sfr[s16][rg];
                if (islocal) s += bf2f(relb[k - q + 2047]) + bf2f(bias[kk]);
                if (diag && k > q) s = -1e30f;
                sv[s16 * 4 + rg] = s;
                tmax = fmaxf(tmax, s);
            }
        }
        tmax = fmaxf(tmax, __shfl_xor(tmax, 16));
        tmax = fmaxf(tmax, __shfl_xor(tmax, 32));
        float newm = fmaxf(m, tmax);
        float corr = __expf(m - newm);
        float psum = 0.f;
        unsigned short pu[16];
        int nact = (s16max + 1) * 4;
        for (int i = 0; i < nact; ++i) {
            float p = __expf(sv[i] - newm);
            psum += p;
            pu[i] = f2bf(p);
        }
        psum += __shfl_xor(psum, 16);
        psum += __shfl_xor(psum, 32);
        lsum = lsum * corr + psum;
        m = newm;
        acc0 *= corr; acc1 *= corr; acc2 *= corr; acc3 *= corr;

        // ---- P^T -> wave-private LDS [q=16][k=64+pad] ----
#pragma unroll
        for (int s16 = 0; s16 < 4; ++s16) {
            unsigned long long pk = 0ull;
            if (s16 <= s16max)
                pk = (unsigned long long)pu[s16 * 4 + 0] |
                     ((unsigned long long)pu[s16 * 4 + 1] << 16) |
                     ((unsigned long long)pu[s16 * 4 + 2] << 32) |
                     ((unsigned long long)pu[s16 * 4 + 3] << 48);
            *(unsigned long long*)&Pw[l15 * 72 + s16 * 16 + l4 * 4] = pk;
        }

        // ---- PV: O^T[d][q] += V^T[d][k] * P[q][k] ----
#pragma unroll
        for (int half = 0; half < 2; ++half) {
            const bf16x8 pf = *(const bf16x8*)&Pw[l15 * 72 + half * 32 + l4 * 8];
            int cbase = half * 4 + l4;
#pragma unroll
            for (int dblk = 0; dblk < 4; ++dblk) {
                int r = dblk * 16 + l15;
                const bf16x8 vf =
                    *(const bf16x8*)&Vt[r * 64 + ((cbase ^ (r & 7)) << 3)];
                f32x4* ac = dblk == 0 ? &acc0 : dblk == 1 ? &acc1
                          : dblk == 2 ? &acc2 : &acc3;
                *ac = __builtin_amdgcn_mfma_f32_16x16x32_bf16(vf, pf, *ac, 0, 0, 0);
            }
        }

        __syncthreads();   // next tile staged; everyone done with cur
        cur ^= 1;
    }

    // ---- epilogue: O^T -> LDS -> coalesced f32 stores ----
    float invl = 1.0f / lsum;
    float* ob = (float*)(smem + wave * 4352);   // per-wave [16][68] f32
    *(f32x4*)&ob[l15 * 68 + 0  + l4 * 4] = acc0 * invl;
    *(f32x4*)&ob[l15 * 68 + 16 + l4 * 4] = acc1 * invl;
    *(f32x4*)&ob[l15 * 68 + 32 + l4 * 4] = acc2 * invl;
    *(f32x4*)&ob[l15 * 68 + 48 + l4 * 4] = acc3 * invl;
    size_t obase = base + (size_t)qt * 64;
#pragma unroll
    for (int it = 0; it < 4; ++it) {
        int row = lane >> 2;
        int col = (lane & 3) * 16 + it * 4;
        f32x4 o = *(const f32x4*)&ob[row * 68 + col];
        *(f32x4*)(out + obase + (size_t)row * 64 + col) = o;
    }
}

extern "C" void kernel_launch(void* const* d_in, const int* in_sizes, int n_in,
                              void* d_out, int out_size, void* d_ws, size_t ws_size,
                              hipStream_t stream) {
    const float* query = (const float*)d_in[0];
    const float* key = (const float*)d_in[1];
    const float* value = (const float*)d_in[2];
    const float* rel_pos_w = (const float*)d_in[5];
    const float* mlp_w = (const float*)d_in[8];
    float* out = (float*)d_out;

    unsigned short* Kb = (unsigned short*)d_ws;      // 32*32*4096 u16 = 8 MiB
    unsigned short* Vtb = Kb + 32 * 32 * 4096;       // 8 MiB
    unsigned short* rel_sb = Vtb + 32 * 32 * 4096;   // 4*4096 u16
    unsigned short* vtb = rel_sb + 4 * 4096;         // 32*2048 u16

    relscore_kernel<<<4095, 256, 0, stream>>>(rel_pos_w, mlp_w, rel_sb);
    vterm_kernel<<<8192, 256, 0, stream>>>(value, mlp_w, vtb);
    preconv_kernel<<<1024, 256, 0, stream>>>(key, value, Kb, Vtb);
    attn_kernel<<<1024, 256, 0, stream>>>(query, Kb, Vtb, rel_sb, vtb, out);
}

// Round 3
// 92.243 us; speedup vs baseline: 3.9156x; 3.9156x over previous
//
#include <hip/hip_runtime.h>

#define TL 2048
#define NHEAD 8
#define NLOC 4
#define L2E 1.44269504f

typedef __attribute__((ext_vector_type(4))) float f32x4;
typedef __attribute__((ext_vector_type(8))) __bf16 bf16x8;
typedef __attribute__((ext_vector_type(8))) unsigned short u16x8;

static __device__ __forceinline__ unsigned short f2bf(float f) {
    unsigned u = __float_as_uint(f);
    u = (u + 0x7FFFu + ((u >> 16) & 1u)) >> 16;
    return (unsigned short)u;
}
static __device__ __forceinline__ float bf2f(unsigned short u) {
    return __uint_as_float(((unsigned)u) << 16);
}
static __device__ __forceinline__ void gl_lds16(const void* g, void* l) {
    __builtin_amdgcn_global_load_lds(
        (const __attribute__((address_space(1))) void*)g,
        (__attribute__((address_space(3))) void*)l, 16, 0, 0);
}

// rel_scores[h', r] = dot(rel_pos_w[r, h'*64:+64], mlp_w[h']) * log2e -> bf16
__global__ __launch_bounds__(256) void relscore_kernel(
    const float* __restrict__ rel_pos_w, const float* __restrict__ mlp_w,
    unsigned short* __restrict__ rel_sb) {
    int r = blockIdx.x;      // 0..4094
    int t = threadIdx.x;
    int w = t >> 6, lane = t & 63;
    float v = rel_pos_w[r * 256 + t] * mlp_w[t];
#pragma unroll
    for (int off = 32; off; off >>= 1) v += __shfl_xor(v, off);
    if (lane == 0) rel_sb[w * 4096 + r] = f2bf(v * L2E);
}

// v_term[(b*4+h')*L + k] = dot(value[b,4+h',k,:], mlp_w[h']) * log2e -> bf16
__global__ __launch_bounds__(256) void vterm_kernel(
    const float* __restrict__ value, const float* __restrict__ mlp_w,
    unsigned short* __restrict__ vtb) {
    int t = threadIdx.x;
    int lane = t & 63;
    int w = blockIdx.x * 4 + (t >> 6);
    int k = w & (TL - 1);
    int hp = (w >> 11) & 3;
    int b = w >> 13;
    float v = value[((size_t)((b * NHEAD + NLOC + hp) * TL + k) << 6) + lane] *
              mlp_w[hp * 64 + lane];
#pragma unroll
    for (int off = 32; off; off >>= 1) v += __shfl_xor(v, off);
    if (lane == 0) vtb[w] = f2bf(v * L2E);
}

// Per (bh, kt): K tile -> bf16 swizzled [64 k][8 chunks], V tile -> bf16
// transposed+swizzled [64 d][8 chunks].  Chunk c of row r stored at c^(r&7).
__global__ __launch_bounds__(256) void preconv_kernel(
    const float* __restrict__ key, const float* __restrict__ value,
    unsigned short* __restrict__ Kb, unsigned short* __restrict__ Vtb) {
    __shared__ float Vf[64][66];
    int blk = blockIdx.x;            // bh*32 + kt
    int t = threadIdx.x;
    size_t src = (size_t)blk * 4096;
    size_t dst = (size_t)blk * 4096;

#pragma unroll
    for (int i = 0; i < 2; ++i) {
        int ch = t + i * 256;
        int row = ch >> 3, c = ch & 7;
        const float* kp = key + src + row * 64 + c * 8;
        f32x4 a = *(const f32x4*)kp;
        f32x4 bb = *(const f32x4*)(kp + 4);
        u16x8 o;
#pragma unroll
        for (int j = 0; j < 4; ++j) { o[j] = f2bf(a[j]); o[4 + j] = f2bf(bb[j]); }
        *(u16x8*)&Kb[dst + row * 64 + ((c ^ (row & 7)) << 3)] = o;
    }
    {
        int row = t >> 2, q4 = t & 3;
        const float* vp = value + src + row * 64 + q4 * 16;
#pragma unroll
        for (int j = 0; j < 4; ++j)
            *(f32x4*)&Vf[row][q4 * 16 + j * 4] = *(const f32x4*)(vp + j * 4);
    }
    __syncthreads();
#pragma unroll
    for (int i = 0; i < 2; ++i) {
        int ch = t + i * 256;
        int dr = ch >> 3, c = ch & 7;
        u16x8 o;
#pragma unroll
        for (int j = 0; j < 8; ++j) o[j] = f2bf(Vf[c * 8 + j][dr]);
        *(u16x8*)&Vtb[dst + dr * 64 + ((c ^ (dr & 7)) << 3)] = o;
    }
}

// Flash attention: 1 block = 1 (b,h) x 64 q-rows; 4 waves x 16 q each.
// Double-buffered global_load_lds staging; P overlaid into dead Ks[cur].
__global__ __launch_bounds__(256, 4) void attn_kernel(
    const float* __restrict__ query,
    const unsigned short* __restrict__ Kb, const unsigned short* __restrict__ Vtb,
    const unsigned short* __restrict__ rel_sb, const unsigned short* __restrict__ vtb,
    float* __restrict__ out) {

    __shared__ __align__(16) unsigned char smem[37248];
    unsigned short* Ks0  = (unsigned short*)smem;             // [2][4096] u16
    unsigned short* Vt0  = (unsigned short*)(smem + 16384);   // [2][4096] u16
    unsigned short* relb = (unsigned short*)(smem + 32768);   // [2112] bf16
    unsigned short* bias0 = (unsigned short*)(smem + 36992);  // [2][64] bf16

    int bid = blockIdx.x;
    int qbi = bid >> 5;
    int bh = bid & 31;
    // snake: every set of CUs gets a constant tile-count sum (load balance)
    int qb = (qbi < 16) ? (31 - qbi) : (qbi - 16);
    int h = bh & 7;
    int b = bh >> 3;
    int q0 = qb << 6;
    int t = threadIdx.x;
    int wave = t >> 6, lane = t & 63;
    int l15 = lane & 15, l4 = lane >> 4;
    bool islocal = (h >= NLOC);

    size_t base = (size_t)bh * TL * 64;
    const unsigned short* Ktiles = Kb + (size_t)bh * 32 * 4096;
    const unsigned short* Vtiles = Vtb + (size_t)bh * 32 * 4096;
    const unsigned short* vtp =
        vtb + (islocal ? (size_t)((b * NLOC + h - NLOC) * TL) : 0);

    // ---- prologue: async-stage tile 0; copy relb (only [0,2112)) + bias[0] ----
    gl_lds16(Ktiles + t * 8, Ks0 + t * 8);
    gl_lds16(Ktiles + 2048 + t * 8, Ks0 + 2048 + t * 8);
    gl_lds16(Vtiles + t * 8, Vt0 + t * 8);
    gl_lds16(Vtiles + 2048 + t * 8, Vt0 + 2048 + t * 8);
    if (islocal) {
        const u16x8* src = (const u16x8*)(rel_sb + (h - NLOC) * 4096);
        u16x8* dst = (u16x8*)relb;
        dst[t] = src[t];
        if (t < 8) {
            dst[256 + t] = src[256 + t];
            *(u16x8*)&bias0[t * 8] = *(const u16x8*)&vtp[t * 8];
        }
    }

    int qt = q0 + wave * 16;
    int q = qt + l15;

    // Q fragments, pre-scaled by (1/sqrt(dk)) * log2e
    const float SC = 0.125f * L2E;
    bf16x8 qf0, qf1;
    {
        const float* qsrc = query + base + (size_t)q * 64 + l4 * 8;
        f32x4 a = *(const f32x4*)qsrc;
        f32x4 bb = *(const f32x4*)(qsrc + 4);
        f32x4 c = *(const f32x4*)(qsrc + 32);
        f32x4 d = *(const f32x4*)(qsrc + 36);
        u16x8 u0, u1;
#pragma unroll
        for (int j = 0; j < 4; ++j) {
            u0[j] = f2bf(a[j] * SC); u0[4 + j] = f2bf(bb[j] * SC);
            u1[j] = f2bf(c[j] * SC); u1[4 + j] = f2bf(d[j] * SC);
        }
        qf0 = __builtin_bit_cast(bf16x8, u0);
        qf1 = __builtin_bit_cast(bf16x8, u1);
    }

    float m = -1e30f, lsum = 0.0f;
    f32x4 acc0 = {0.f, 0.f, 0.f, 0.f};
    f32x4 acc1 = acc0, acc2 = acc0, acc3 = acc0;

    __syncthreads();   // tile 0 + relb + bias ready

    int cur = 0;
    for (int kt = 0; kt <= qb; ++kt) {
        unsigned short* Ks = Ks0 + cur * 4096;
        unsigned short* Vt = Vt0 + cur * 4096;
        unsigned short* bias = bias0 + cur * 64;

        // ---- prefetch tile kt+1 into the other buffer (async) ----
        if (kt < qb) {
            int nb = cur ^ 1;
            const unsigned short* gk = Ktiles + (size_t)(kt + 1) * 4096;
            const unsigned short* gv = Vtiles + (size_t)(kt + 1) * 4096;
            gl_lds16(gk + t * 8, Ks0 + nb * 4096 + t * 8);
            gl_lds16(gk + 2048 + t * 8, Ks0 + nb * 4096 + 2048 + t * 8);
            gl_lds16(gv + t * 8, Vt0 + nb * 4096 + t * 8);
            gl_lds16(gv + 2048 + t * 8, Vt0 + nb * 4096 + 2048 + t * 8);
            if (islocal && t < 8)
                *(u16x8*)&bias0[nb * 64 + t * 8] =
                    *(const u16x8*)&vtp[(kt + 1) * 64 + t * 8];
        }

        int k0 = kt << 6;
        bool diag = (kt == qb);
        int s16max = diag ? wave : 3;   // wave-uniform; loops stay UNROLLED

        // ---- S^T = mfma(K, Q): row = k, col = q ----
        f32x4 sfr[4];
#pragma unroll
        for (int s16 = 0; s16 < 4; ++s16) {
            if (s16 <= s16max) {
                int r = s16 * 16 + l15;
                int sw = r & 7;
                const bf16x8 kf0 = *(const bf16x8*)&Ks[r * 64 + ((l4 ^ sw) << 3)];
                const bf16x8 kf1 = *(const bf16x8*)&Ks[r * 64 + (((4 + l4) ^ sw) << 3)];
                f32x4 z = {0.f, 0.f, 0.f, 0.f};
                z = __builtin_amdgcn_mfma_f32_16x16x32_bf16(kf0, qf0, z, 0, 0, 0);
                z = __builtin_amdgcn_mfma_f32_16x16x32_bf16(kf1, qf1, z, 0, 0, 0);
                sfr[s16] = z;
            } else {
                sfr[s16] = (f32x4){-1e30f, -1e30f, -1e30f, -1e30f};
            }
        }

        // ---- online softmax in exp2 domain (per-lane q-row state) ----
        float sv[16];
        float tmax = -1e30f;
#pragma unroll
        for (int s16 = 0; s16 < 4; ++s16) {
#pragma unroll
            for (int rg = 0; rg < 4; ++rg) {
                int kk = s16 * 16 + l4 * 4 + rg;
                int k = k0 + kk;
                float s = sfr[s16][rg];
                if (s16 <= s16max) {
                    if (islocal) s += bf2f(relb[k - q + 2047]) + bf2f(bias[kk]);
                    if (diag && k > q) s = -1e30f;
                }
                sv[s16 * 4 + rg] = s;
                tmax = fmaxf(tmax, s);
            }
        }
        tmax = fmaxf(tmax, __shfl_xor(tmax, 16));
        tmax = fmaxf(tmax, __shfl_xor(tmax, 32));
        float newm = fmaxf(m, tmax);
        float corr = exp2f(m - newm);
        float psum = 0.f;
        unsigned short pu[16];
#pragma unroll
        for (int i = 0; i < 16; ++i) {
            float p = exp2f(sv[i] - newm);
            psum += p;
            pu[i] = f2bf(p);
        }
        psum += __shfl_xor(psum, 16);
        psum += __shfl_xor(psum, 32);
        lsum = lsum * corr + psum;
        m = newm;
        acc0 *= corr; acc1 *= corr; acc2 *= corr; acc3 *= corr;

        __syncthreads();   // all waves done reading Ks[cur] -> safe to overlay P

        // ---- P -> overlay into dead Ks[cur], wave-private [16 q][8 chunks] ----
        unsigned short* Pw = Ks + wave * 1024;
#pragma unroll
        for (int s16 = 0; s16 < 4; ++s16) {
            unsigned long long pk =
                (unsigned long long)pu[s16 * 4 + 0] |
                ((unsigned long long)pu[s16 * 4 + 1] << 16) |
                ((unsigned long long)pu[s16 * 4 + 2] << 32) |
                ((unsigned long long)pu[s16 * 4 + 3] << 48);
            int c = 2 * s16 + (l4 >> 1);
            Pw[l15 * 64 + ((c ^ (l15 & 7)) << 3) + ((l4 & 1) << 2)] = 0; // keep addr alive
            *(unsigned long long*)&Pw[l15 * 64 + ((c ^ (l15 & 7)) << 3) + ((l4 & 1) << 2)] = pk;
        }

        // ---- PV: O^T[d][q] += V^T[d][k] * P[q][k] ----
#pragma unroll
        for (int half = 0; half < 2; ++half) {
            const bf16x8 pf =
                *(const bf16x8*)&Pw[l15 * 64 + (((half * 4 + l4) ^ (l15 & 7)) << 3)];
            int cbase = half * 4 + l4;
#pragma unroll
            for (int dblk = 0; dblk < 4; ++dblk) {
                int r = dblk * 16 + l15;
                const bf16x8 vf =
                    *(const bf16x8*)&Vt[r * 64 + ((cbase ^ (r & 7)) << 3)];
                f32x4* ac = dblk == 0 ? &acc0 : dblk == 1 ? &acc1
                          : dblk == 2 ? &acc2 : &acc3;
                *ac = __builtin_amdgcn_mfma_f32_16x16x32_bf16(vf, pf, *ac, 0, 0, 0);
            }
        }

        __syncthreads();   // next tile staged; everyone past PV before overwrite
        cur ^= 1;
    }

    // ---- epilogue: O^T -> LDS -> coalesced f32 stores ----
    float invl = 1.0f / lsum;
    float* ob = (float*)(smem + wave * 4352);   // per-wave [16][68] f32
    *(f32x4*)&ob[l15 * 68 + 0  + l4 * 4] = acc0 * invl;
    *(f32x4*)&ob[l15 * 68 + 16 + l4 * 4] = acc1 * invl;
    *(f32x4*)&ob[l15 * 68 + 32 + l4 * 4] = acc2 * invl;
    *(f32x4*)&ob[l15 * 68 + 48 + l4 * 4] = acc3 * invl;
    size_t obase = base + (size_t)qt * 64;
#pragma unroll
    for (int it = 0; it < 4; ++it) {
        int row = lane >> 2;
        int col = (lane & 3) * 16 + it * 4;
        f32x4 o = *(const f32x4*)&ob[row * 68 + col];
        *(f32x4*)(out + obase + (size_t)row * 64 + col) = o;
    }
}

extern "C" void kernel_launch(void* const* d_in, const int* in_sizes, int n_in,
                              void* d_out, int out_size, void* d_ws, size_t ws_size,
                              hipStream_t stream) {
    const float* query = (const float*)d_in[0];
    const float* key = (const float*)d_in[1];
    const float* value = (const float*)d_in[2];
    const float* rel_pos_w = (const float*)d_in[5];
    const float* mlp_w = (const float*)d_in[8];
    float* out = (float*)d_out;

    unsigned short* Kb = (unsigned short*)d_ws;      // 32*32*4096 u16 = 8 MiB
    unsigned short* Vtb = Kb + 32 * 32 * 4096;       // 8 MiB
    unsigned short* rel_sb = Vtb + 32 * 32 * 4096;   // 4*4096 u16
    unsigned short* vtb = rel_sb + 4 * 4096;         // 32*2048 u16

    relscore_kernel<<<4095, 256, 0, stream>>>(rel_pos_w, mlp_w, rel_sb);
    vterm_kernel<<<8192, 256, 0, stream>>>(value, mlp_w, vtb);
    preconv_kernel<<<1024, 256, 0, stream>>>(key, value, Kb, Vtb);
    attn_kernel<<<1024, 256, 0, stream>>>(query, Kb, Vtb, rel_sb, vtb, out);
}

// Round 4
// 88.954 us; speedup vs baseline: 4.0604x; 1.0370x over previous
//
#include <hip/hip_runtime.h>

#define TL 2048
#define NHEAD 8
#define NLOC 4
#define L2E 1.44269504f

typedef __attribute__((ext_vector_type(4))) float f32x4;
typedef __attribute__((ext_vector_type(8))) __bf16 bf16x8;
typedef __attribute__((ext_vector_type(4))) __bf16 bf16x4;
typedef __attribute__((ext_vector_type(8))) unsigned short u16x8;

static __device__ __forceinline__ unsigned short f2bf(float f) {
    unsigned u = __float_as_uint(f);
    u = (u + 0x7FFFu + ((u >> 16) & 1u)) >> 16;
    return (unsigned short)u;
}
static __device__ __forceinline__ float bf2f(unsigned short u) {
    return __uint_as_float(((unsigned)u) << 16);
}
static __device__ __forceinline__ void gl_lds16(const void* g, void* l) {
    __builtin_amdgcn_global_load_lds(
        (const __attribute__((address_space(1))) void*)g,
        (__attribute__((address_space(3))) void*)l, 16, 0, 0);
}

// rel_scores[h', r] = dot(rel_pos_w[r, h'*64:+64], mlp_w[h']) * log2e -> bf16
__global__ __launch_bounds__(256) void relscore_kernel(
    const float* __restrict__ rel_pos_w, const float* __restrict__ mlp_w,
    unsigned short* __restrict__ rel_sb) {
    int r = blockIdx.x;      // 0..4094
    int t = threadIdx.x;
    int w = t >> 6, lane = t & 63;
    float v = rel_pos_w[r * 256 + t] * mlp_w[t];
#pragma unroll
    for (int off = 32; off; off >>= 1) v += __shfl_xor(v, off);
    if (lane == 0) rel_sb[w * 4096 + r] = f2bf(v * L2E);
}

// Per (bh, kt): K tile -> bf16 swizzled [64 k][8 chunks], V tile -> bf16
// transposed+swizzled [64 d][8 chunks]; chunk c of row r stored at c^(r&7).
// Also fused: v_term[(b*4+h')*L + k] = dot(V[k,:], mlp_w[h']) * log2e (local h).
__global__ __launch_bounds__(256) void preconv_kernel(
    const float* __restrict__ key, const float* __restrict__ value,
    const float* __restrict__ mlp_w,
    unsigned short* __restrict__ Kb, unsigned short* __restrict__ Vtb,
    unsigned short* __restrict__ vtb) {
    __shared__ float Vf[64][66];
    int blk = blockIdx.x;            // bh*32 + kt
    int t = threadIdx.x;
    int bh = blk >> 5, kt = blk & 31;
    int h = bh & 7, b = bh >> 3;
    size_t src = (size_t)blk * 4096;
    size_t dst = (size_t)blk * 4096;

    // K: direct convert, swizzled store
#pragma unroll
    for (int i = 0; i < 2; ++i) {
        int ch = t + i * 256;
        int row = ch >> 3, c = ch & 7;
        const float* kp = key + src + row * 64 + c * 8;
        f32x4 a = *(const f32x4*)kp;
        f32x4 bb = *(const f32x4*)(kp + 4);
        u16x8 o;
#pragma unroll
        for (int j = 0; j < 4; ++j) { o[j] = f2bf(a[j]); o[4 + j] = f2bf(bb[j]); }
        *(u16x8*)&Kb[dst + row * 64 + ((c ^ (row & 7)) << 3)] = o;
    }
    // V: coalesced load to LDS
    {
        int row = t >> 2, q4 = t & 3;
        const float* vp = value + src + row * 64 + q4 * 16;
#pragma unroll
        for (int j = 0; j < 4; ++j)
            *(f32x4*)&Vf[row][q4 * 16 + j * 4] = *(const f32x4*)(vp + j * 4);
    }
    __syncthreads();
    // V transpose, swizzled store
#pragma unroll
    for (int i = 0; i < 2; ++i) {
        int ch = t + i * 256;
        int dr = ch >> 3, c = ch & 7;
        u16x8 o;
#pragma unroll
        for (int j = 0; j < 8; ++j) o[j] = f2bf(Vf[c * 8 + j][dr]);
        *(u16x8*)&Vtb[dst + dr * 64 + ((c ^ (dr & 7)) << 3)] = o;
    }
    // fused v_term for local heads
    if (h >= NLOC) {
        int wave = t >> 6, lane = t & 63;
        float mw = mlp_w[(h - NLOC) * 64 + lane];
        unsigned short* vout = vtb + (size_t)((b * NLOC + h - NLOC) * TL) + kt * 64;
#pragma unroll
        for (int i = 0; i < 16; ++i) {
            int row = wave * 16 + i;
            float v = Vf[row][lane] * mw;
#pragma unroll
            for (int off = 32; off; off >>= 1) v += __shfl_xor(v, off);
            if (lane == 0) vout[row] = f2bf(v * L2E);
        }
    }
}

// Flash attention: 1 block = 1 (b,h) x 64 q-rows; 4 waves x 16 q each.
// Double-buffered global_load_lds staging; P overlaid into dead Ks[cur].
// Mid barrier is raw s_barrier + lgkmcnt(0) only (no vmcnt drain of prefetch).
__global__ __launch_bounds__(256, 4) void attn_kernel(
    const float* __restrict__ query,
    const unsigned short* __restrict__ Kb, const unsigned short* __restrict__ Vtb,
    const unsigned short* __restrict__ rel_sb, const unsigned short* __restrict__ vtb,
    float* __restrict__ out) {

    __shared__ __align__(16) unsigned char smem[37248];
    unsigned short* Ks0  = (unsigned short*)smem;             // [2][4096] u16
    unsigned short* Vt0  = (unsigned short*)(smem + 16384);   // [2][4096] u16
    unsigned short* relb = (unsigned short*)(smem + 32768);   // [2112] bf16
    unsigned short* bias0 = (unsigned short*)(smem + 36992);  // [2][64] bf16

    int bid = blockIdx.x;
    int qbi = bid >> 5;
    int bh = bid & 31;
    // snake: constant tile-count sum per CU group (load balance)
    int qb = (qbi < 16) ? (31 - qbi) : (qbi - 16);
    int h = bh & 7;
    int b = bh >> 3;
    int q0 = qb << 6;
    int t = threadIdx.x;
    int wave = t >> 6, lane = t & 63;
    int l15 = lane & 15, l4 = lane >> 4;
    bool islocal = (h >= NLOC);

    size_t base = (size_t)bh * TL * 64;
    const unsigned short* Ktiles = Kb + (size_t)bh * 32 * 4096;
    const unsigned short* Vtiles = Vtb + (size_t)bh * 32 * 4096;
    const unsigned short* vtp =
        vtb + (islocal ? (size_t)((b * NLOC + h - NLOC) * TL) : 0);

    // ---- prologue: async-stage tile 0; copy relb + bias[0] ----
    gl_lds16(Ktiles + t * 8, Ks0 + t * 8);
    gl_lds16(Ktiles + 2048 + t * 8, Ks0 + 2048 + t * 8);
    gl_lds16(Vtiles + t * 8, Vt0 + t * 8);
    gl_lds16(Vtiles + 2048 + t * 8, Vt0 + 2048 + t * 8);
    if (islocal) {
        const u16x8* src = (const u16x8*)(rel_sb + (h - NLOC) * 4096);
        u16x8* dst = (u16x8*)relb;
        dst[t] = src[t];
        if (t < 8) {
            dst[256 + t] = src[256 + t];
            *(u16x8*)&bias0[t * 8] = *(const u16x8*)&vtp[t * 8];
        }
    }

    int qt = q0 + wave * 16;
    int q = qt + l15;

    // Q fragments, pre-scaled by (1/sqrt(dk)) * log2e
    const float SC = 0.125f * L2E;
    bf16x8 qf0, qf1;
    {
        const float* qsrc = query + base + (size_t)q * 64 + l4 * 8;
        f32x4 a = *(const f32x4*)qsrc;
        f32x4 bb = *(const f32x4*)(qsrc + 4);
        f32x4 c = *(const f32x4*)(qsrc + 32);
        f32x4 d = *(const f32x4*)(qsrc + 36);
        u16x8 u0, u1;
#pragma unroll
        for (int j = 0; j < 4; ++j) {
            u0[j] = f2bf(a[j] * SC); u0[4 + j] = f2bf(bb[j] * SC);
            u1[j] = f2bf(c[j] * SC); u1[4 + j] = f2bf(d[j] * SC);
        }
        qf0 = __builtin_bit_cast(bf16x8, u0);
        qf1 = __builtin_bit_cast(bf16x8, u1);
    }

    float m = -1e30f, lsum = 0.0f;
    f32x4 acc0 = {0.f, 0.f, 0.f, 0.f};
    f32x4 acc1 = acc0, acc2 = acc0, acc3 = acc0;

    __syncthreads();   // tile 0 + relb + bias ready

    int cur = 0;
    for (int kt = 0; kt <= qb; ++kt) {
        unsigned short* Ks = Ks0 + cur * 4096;
        unsigned short* Vt = Vt0 + cur * 4096;
        unsigned short* bias = bias0 + cur * 64;

        // ---- prefetch tile kt+1 into the other buffer (async) ----
        if (kt < qb) {
            int nb = cur ^ 1;
            const unsigned short* gk = Ktiles + (size_t)(kt + 1) * 4096;
            const unsigned short* gv = Vtiles + (size_t)(kt + 1) * 4096;
            gl_lds16(gk + t * 8, Ks0 + nb * 4096 + t * 8);
            gl_lds16(gk + 2048 + t * 8, Ks0 + nb * 4096 + 2048 + t * 8);
            gl_lds16(gv + t * 8, Vt0 + nb * 4096 + t * 8);
            gl_lds16(gv + 2048 + t * 8, Vt0 + nb * 4096 + 2048 + t * 8);
            if (islocal && t < 8)
                *(u16x8*)&bias0[nb * 64 + t * 8] =
                    *(const u16x8*)&vtp[(kt + 1) * 64 + t * 8];
        }

        int k0 = kt << 6;
        bool diag = (kt == qb);
        int s16max = diag ? wave : 3;   // wave-uniform; loops stay UNROLLED

        // ---- S^T = mfma(K, Q): row = k, col = q ----
        f32x4 sfr[4];
#pragma unroll
        for (int s16 = 0; s16 < 4; ++s16) {
            if (s16 <= s16max) {
                int r = s16 * 16 + l15;
                int sw = r & 7;
                const bf16x8 kf0 = *(const bf16x8*)&Ks[r * 64 + ((l4 ^ sw) << 3)];
                const bf16x8 kf1 = *(const bf16x8*)&Ks[r * 64 + (((4 + l4) ^ sw) << 3)];
                f32x4 z = {0.f, 0.f, 0.f, 0.f};
                z = __builtin_amdgcn_mfma_f32_16x16x32_bf16(kf0, qf0, z, 0, 0, 0);
                z = __builtin_amdgcn_mfma_f32_16x16x32_bf16(kf1, qf1, z, 0, 0, 0);
                sfr[s16] = z;
            } else {
                sfr[s16] = (f32x4){-1e30f, -1e30f, -1e30f, -1e30f};
            }
        }

        // ---- online softmax in exp2 domain (per-lane q-row state) ----
        float sv[16];
        float tmax = -1e30f;
#pragma unroll
        for (int s16 = 0; s16 < 4; ++s16) {
#pragma unroll
            for (int rg = 0; rg < 4; ++rg) {
                int kk = s16 * 16 + l4 * 4 + rg;
                int k = k0 + kk;
                float s = sfr[s16][rg];
                if (s16 <= s16max) {
                    if (islocal) s += bf2f(relb[k - q + 2047]) + bf2f(bias[kk]);
                    if (diag && k > q) s = -1e30f;
                }
                sv[s16 * 4 + rg] = s;
                tmax = fmaxf(tmax, s);
            }
        }
        tmax = fmaxf(tmax, __shfl_xor(tmax, 16));
        tmax = fmaxf(tmax, __shfl_xor(tmax, 32));
        // defer-max (T13): rescale only when the running max is exceeded by >THR
        if (__any(tmax > m + 11.5f)) {
            float newm = fmaxf(m, tmax);
            float corr = exp2f(m - newm);
            lsum *= corr;
            acc0 *= corr; acc1 *= corr; acc2 *= corr; acc3 *= corr;
            m = newm;
        }
        float psum = 0.f;
        bf16x4 pq[4];
#pragma unroll
        for (int s16 = 0; s16 < 4; ++s16) {
#pragma unroll
            for (int rg = 0; rg < 4; ++rg) {
                float p = exp2f(sv[s16 * 4 + rg] - m);
                psum += p;
                pq[s16][rg] = (__bf16)p;
            }
        }
        psum += __shfl_xor(psum, 16);
        psum += __shfl_xor(psum, 32);
        lsum += psum;

        // mid barrier: all waves' QK^T ds_reads done -> safe to overlay P.
        // lgkmcnt ONLY — do NOT drain the in-flight gl_lds prefetch (vmcnt).
        asm volatile("s_waitcnt lgkmcnt(0)" ::: "memory");
        __builtin_amdgcn_s_barrier();
        __builtin_amdgcn_sched_barrier(0);

        // ---- P -> overlay into dead Ks[cur], wave-private [16 q][8 chunks] ----
        unsigned short* Pw = Ks + wave * 1024;
#pragma unroll
        for (int s16 = 0; s16 < 4; ++s16) {
            int c = 2 * s16 + (l4 >> 1);
            *(unsigned long long*)&Pw[l15 * 64 + ((c ^ (l15 & 7)) << 3) + ((l4 & 1) << 2)] =
                __builtin_bit_cast(unsigned long long, pq[s16]);
        }

        // ---- PV: O^T[d][q] += V^T[d][k] * P[q][k] ----
#pragma unroll
        for (int half = 0; half < 2; ++half) {
            const bf16x8 pf =
                *(const bf16x8*)&Pw[l15 * 64 + (((half * 4 + l4) ^ (l15 & 7)) << 3)];
            int cbase = half * 4 + l4;
#pragma unroll
            for (int dblk = 0; dblk < 4; ++dblk) {
                int r = dblk * 16 + l15;
                const bf16x8 vf =
                    *(const bf16x8*)&Vt[r * 64 + ((cbase ^ (r & 7)) << 3)];
                f32x4* ac = dblk == 0 ? &acc0 : dblk == 1 ? &acc1
                          : dblk == 2 ? &acc2 : &acc3;
                *ac = __builtin_amdgcn_mfma_f32_16x16x32_bf16(vf, pf, *ac, 0, 0, 0);
            }
        }

        __syncthreads();   // next tile staged (vmcnt+lgkm drain); PV done
        cur ^= 1;
    }

    // ---- epilogue: O^T -> LDS -> coalesced f32 stores ----
    float invl = 1.0f / lsum;
    float* ob = (float*)(smem + wave * 4352);   // per-wave [16][68] f32
    *(f32x4*)&ob[l15 * 68 + 0  + l4 * 4] = acc0 * invl;
    *(f32x4*)&ob[l15 * 68 + 16 + l4 * 4] = acc1 * invl;
    *(f32x4*)&ob[l15 * 68 + 32 + l4 * 4] = acc2 * invl;
    *(f32x4*)&ob[l15 * 68 + 48 + l4 * 4] = acc3 * invl;
    size_t obase = base + (size_t)qt * 64;
#pragma unroll
    for (int it = 0; it < 4; ++it) {
        int row = lane >> 2;
        int col = (lane & 3) * 16 + it * 4;
        f32x4 o = *(const f32x4*)&ob[row * 68 + col];
        *(f32x4*)(out + obase + (size_t)row * 64 + col) = o;
    }
}

extern "C" void kernel_launch(void* const* d_in, const int* in_sizes, int n_in,
                              void* d_out, int out_size, void* d_ws, size_t ws_size,
                              hipStream_t stream) {
    const float* query = (const float*)d_in[0];
    const float* key = (const float*)d_in[1];
    const float* value = (const float*)d_in[2];
    const float* rel_pos_w = (const float*)d_in[5];
    const float* mlp_w = (const float*)d_in[8];
    float* out = (float*)d_out;

    unsigned short* Kb = (unsigned short*)d_ws;      // 32*32*4096 u16 = 8 MiB
    unsigned short* Vtb = Kb + 32 * 32 * 4096;       // 8 MiB
    unsigned short* rel_sb = Vtb + 32 * 32 * 4096;   // 4*4096 u16
    unsigned short* vtb = rel_sb + 4 * 4096;         // 32*2048 u16

    relscore_kernel<<<4095, 256, 0, stream>>>(rel_pos_w, mlp_w, rel_sb);
    preconv_kernel<<<1024, 256, 0, stream>>>(key, value, mlp_w, Kb, Vtb, vtb);
    attn_kernel<<<1024, 256, 0, stream>>>(query, Kb, Vtb, rel_sb, vtb, out);
}